// Round 9
// baseline (33.523 us; speedup 1.0000x reference)
//
#include <hip/hip_runtime.h>
#include <math.h>

#define TPB 512
#define WAVES 8
#define RAYS_PB 256      // rays per block
#define RPT 4            // rays per thread (RAYS_PB / 64)
#define PREP_BLK 16      // prep blocks per batch
#define PREP_T 128

// ---------------------------------------------------------------------------
// Prep: pack points as (qx,qy,qz,-0.5|q|^2); per-block maxdist^2 partials.
// grid = (PREP_BLK, B), block = 128. No atomics, no memset.
// ---------------------------------------------------------------------------
__global__ __launch_bounds__(PREP_T) void prep_kernel(
    const float* __restrict__ c, const float* __restrict__ pc,
    float4* __restrict__ pts4, float* __restrict__ gpart, int N)
{
    int b = blockIdx.y, blk = blockIdx.x;
    const float* cb = c + b * 25;
    float ox = cb[3], oy = cb[7], oz = cb[11];
    const float* p = pc + (size_t)b * N * 3;
    int per = (N + PREP_BLK - 1) / PREP_BLK;
    int n0 = blk * per;
    int n1 = min(n0 + per, N);
    float mx = 0.0f;   // squared distances >= 0
    for (int n = n0 + threadIdx.x; n < n1; n += PREP_T) {
        float qx = p[n * 3], qy = p[n * 3 + 1], qz = p[n * 3 + 2];
        float qn = qx * qx + qy * qy + qz * qz;
        pts4[(size_t)b * N + n] = make_float4(qx, qy, qz, -0.5f * qn);
        float dx = qx - ox, dy = qy - oy, dz = qz - oz;
        mx = fmaxf(mx, dx * dx + dy * dy + dz * dz);
    }
    for (int off = 32; off; off >>= 1) mx = fmaxf(mx, __shfl_down(mx, off));
    __shared__ float sm[PREP_T / 64];
    if ((threadIdx.x & 63) == 0) sm[threadIdx.x >> 6] = mx;
    __syncthreads();
    if (threadIdx.x == 0) {
        float m2 = sm[0];
        for (int i = 1; i < PREP_T / 64; ++i) m2 = fmaxf(m2, sm[i]);
        gpart[b * PREP_BLK + blk] = m2;
    }
}

// ---------------------------------------------------------------------------
// Main: grid = (ceil(M/256), B), block = 512 (8 waves). NO LDS point staging.
// Each wave scans its own N/8 point chunk through WAVE-UNIFORM addresses
// (readfirstlane'd base/count) -> scalar s_load broadcasts on the idle
// scalar pipe; the LDS/VMEM pipes stay free. 4 rays/thread in registers;
// 2 points/iter (v_max3 fusion). Cross-wave max combine in LDS; masked sum
// -> ONE float2 per block. Deterministic: fixed-order reductions, no atomics.
//   min_n d2 = pn - 2 * max_n (p.q - 0.5|q|^2),  q.w = -0.5|q|^2
// ---------------------------------------------------------------------------
__global__ __launch_bounds__(TPB) void chamfer_main(
    const float* __restrict__ c, const float* __restrict__ depth,
    const float4* __restrict__ pts4, const float* __restrict__ gpart,
    float2* __restrict__ partial, int res, int M, int N)
{
    __shared__ float red[WAVES][RAYS_PB];     // 8 KB
    __shared__ float bs[RPT], bc[RPT];

    int tile = blockIdx.x, b = blockIdx.y;
    int tid = threadIdx.x, w = tid >> 6, lane = tid & 63;

    const float* cb = c + b * 25;
    float fx = cb[16], sk = cb[17], cx = cb[18];
    float fy = cb[20], cy = cb[21];
    float ox = cb[3], oy = cb[7], oz = cb[11];

    // maxdist threshold (uniform scalar loads)
    float m2 = 0.0f;
    #pragma unroll
    for (int i = 0; i < PREP_BLK; ++i) m2 = fmaxf(m2, gpart[b * PREP_BLK + i]);
    float thr = sqrtf(m2);

    // ---- ray setup: 4 rays per thread ----
    float px[RPT], py[RPT], pz[RPT], pn[RPT], dep[RPT], mxs[RPT];
    #pragma unroll
    for (int r = 0; r < RPT; ++r) {
        int m = tile * RAYS_PB + lane + 64 * r;
        int mm = min(m, M - 1);
        int i = mm / res, j = mm - i * res;
        float x = (j + 0.5f) / (float)res;
        float y = (i + 0.5f) / (float)res;
        float xl = (x - cx + cy * sk / fy - sk * y / fy) / fx;
        float yl = (y - cy) / fy;
        float wx = cb[0] * xl + cb[1] * yl + cb[2] + cb[3];
        float wy = cb[4] * xl + cb[5] * yl + cb[6] + cb[7];
        float wz = cb[8] * xl + cb[9] * yl + cb[10] + cb[11];
        float dx = wx - ox, dy = wy - oy, dz = wz - oz;
        float nrm = fmaxf(sqrtf(dx * dx + dy * dy + dz * dz), 1e-12f);
        dx /= nrm; dy /= nrm; dz /= nrm;
        float d = depth[(size_t)b * M + mm];
        dep[r] = d;
        px[r] = fmaf(d, dx, ox);
        py[r] = fmaf(d, dy, oy);
        pz[r] = fmaf(d, dz, oz);
        pn[r] = px[r] * px[r] + py[r] * py[r] + pz[r] * pz[r];
        mxs[r] = -3.4e38f;
    }

    // ---- this wave's point chunk: wave-uniform scalar-broadcast stream ----
    {
        int cpw = (N + WAVES - 1) / WAVES;
        int s0 = min(w * cpw, N);
        int s1 = min(s0 + cpw, N);
        int s0u = __builtin_amdgcn_readfirstlane(s0);
        int cnt = __builtin_amdgcn_readfirstlane(s1 - s0);
        const float4* __restrict__ sp = pts4 + (size_t)b * N + s0u;
        int k = 0;
        #pragma unroll 4
        for (; k + 1 < cnt; k += 2) {
            float4 qa = sp[k];        // uniform address -> s_load_dwordx4
            float4 qb = sp[k + 1];
            #pragma unroll
            for (int r = 0; r < RPT; ++r) {
                float sa = fmaf(pz[r], qa.z, qa.w);
                sa = fmaf(py[r], qa.y, sa);
                sa = fmaf(px[r], qa.x, sa);
                float sb = fmaf(pz[r], qb.z, qb.w);
                sb = fmaf(py[r], qb.y, sb);
                sb = fmaf(px[r], qb.x, sb);
                mxs[r] = fmaxf(mxs[r], fmaxf(sa, sb));   // -> v_max3_f32
            }
        }
        if (k < cnt) {
            float4 q = sp[k];
            #pragma unroll
            for (int r = 0; r < RPT; ++r) {
                float s = fmaf(pz[r], q.z, q.w);
                s = fmaf(py[r], q.y, s);
                s = fmaf(px[r], q.x, s);
                mxs[r] = fmaxf(mxs[r], s);
            }
        }
    }

    // ---- cross-wave max combine; thread tid (<256) owns ray tid ----
    #pragma unroll
    for (int r = 0; r < RPT; ++r) red[w][lane + 64 * r] = mxs[r];
    __syncthreads();

    float s = 0.f, cnt2 = 0.f;
    if (tid < RAYS_PB) {
        float mx = red[0][tid];
        #pragma unroll
        for (int ww = 1; ww < WAVES; ++ww) mx = fmaxf(mx, red[ww][tid]);
        // ray tid's pn/dep live in this thread's slot r == w (static select)
        float pnk = pn[0], dk = dep[0];
        #pragma unroll
        for (int r = 1; r < RPT; ++r) if (w == r) { pnk = pn[r]; dk = dep[r]; }
        int m = tile * RAYS_PB + tid;
        if (m < M) {
            float md = fmaxf(fmaf(-2.0f, mx, pnk), 0.0f);
            if (dk < thr) { s = md; cnt2 = 1.0f; }
        }
    }
    for (int off = 32; off; off >>= 1) {
        s += __shfl_down(s, off);
        cnt2 += __shfl_down(cnt2, off);
    }
    if (tid < RAYS_PB && lane == 0) { bs[w] = s; bc[w] = cnt2; }
    __syncthreads();
    if (tid == 0) {
        float S = 0.f, C = 0.f;
        #pragma unroll
        for (int ww = 0; ww < RPT; ++ww) { S += bs[ww]; C += bc[ww]; }
        partial[(size_t)b * gridDim.x + blockIdx.x] = make_float2(S, C);
    }
}

// ---------------------------------------------------------------------------
// Finalize: ONE block; wave w reduces batch w's ntiles partials.
// ---------------------------------------------------------------------------
__global__ __launch_bounds__(1024) void finalize_kernel(
    const float2* __restrict__ partial, float* __restrict__ out,
    int ntiles, int B)
{
    int w = threadIdx.x >> 6, lane = threadIdx.x & 63;
    if (w >= B) return;
    float S = 0.f, C = 0.f;
    for (int i = lane; i < ntiles; i += 64) {
        float2 p = partial[(size_t)w * ntiles + i];
        S += p.x; C += p.y;
    }
    for (int off = 32; off; off >>= 1) {
        S += __shfl_down(S, off);
        C += __shfl_down(C, off);
    }
    if (lane == 0) out[w] = S / fmaxf(C, 1.0f);
}

extern "C" void kernel_launch(void* const* d_in, const int* in_sizes, int n_in,
                              void* d_out, int out_size, void* d_ws, size_t ws_size,
                              hipStream_t stream) {
    const float* c     = (const float*)d_in[0];
    const float* depth = (const float*)d_in[1];
    const float* pc    = (const float*)d_in[2];

    int B = in_sizes[0] / 25;
    int M = in_sizes[1] / B;
    int N = in_sizes[2] / (3 * B);
    int res = 1;
    while (res * res < M) ++res;

    char* base = (char*)d_ws;
    float4* pts4 = (float4*)base;
    size_t o = (size_t)B * N * sizeof(float4);
    o = (o + 255) & ~(size_t)255;
    float* gpart = (float*)(base + o);
    o += (size_t)B * PREP_BLK * sizeof(float);
    o = (o + 255) & ~(size_t)255;
    float2* partial = (float2*)(base + o);

    int ntiles = (M + RAYS_PB - 1) / RAYS_PB;

    prep_kernel<<<dim3(PREP_BLK, B), PREP_T, 0, stream>>>(c, pc, pts4, gpart, N);
    chamfer_main<<<dim3(ntiles, B), TPB, 0, stream>>>(c, depth, pts4, gpart,
                                                      partial, res, M, N);
    finalize_kernel<<<1, B * 64, 0, stream>>>(partial, (float*)d_out,
                                              ntiles, B);
}

// Round 10
// 32.402 us; speedup vs baseline: 1.0346x; 1.0346x over previous
//
#include <hip/hip_runtime.h>
#include <math.h>

#define TPB 512
#define WAVES 8
#define RAYS_PB 256      // rays per block
#define RPT 4            // rays per thread (RAYS_PB / 64)
#define PPL 4            // points per lane; wave chunk = 64*PPL = 256

// broadcast lane g's float through the VALU (readlane -> SGPR)
__device__ __forceinline__ float rl(float v, int g) {
    return __int_as_float(__builtin_amdgcn_readlane(__float_as_int(v), g));
}

// ---------------------------------------------------------------------------
// Fused main: grid = (ceil(M/256), B), block = 512 (8 waves).
// Each block: 256 rays vs ALL N points. NO LDS point staging:
//  - each lane loads PPL=4 consecutive points (3x float4, coalesced) into
//    VGPRs, computes qw = -0.5|q|^2 and its maxdist partial in-register
//  - the wave sweeps g = 0..63, broadcasting lane g's 4 points via
//    v_readlane (pure VALU; LDS & VMEM pipes stay idle)
//  - 4 rays/thread in registers; 2 points/update -> v_max3_f32
//  - cross-wave max combine in LDS; masked sum -> ONE float2 per block.
// Deterministic: fixed-order in-block reductions, no atomics.
//   min_n d2 = pn - 2 * max_n (p.q - 0.5|q|^2),  qw = -0.5|q|^2
// ---------------------------------------------------------------------------
__global__ __launch_bounds__(TPB) void chamfer_main(
    const float* __restrict__ c, const float* __restrict__ depth,
    const float* __restrict__ pc, float2* __restrict__ partial,
    int res, int M, int N)
{
    __shared__ float red[WAVES][RAYS_PB];     // 8 KB
    __shared__ float smax[WAVES];
    __shared__ float bs[RAYS_PB / 64], bc[RAYS_PB / 64];

    int tile = blockIdx.x, b = blockIdx.y;
    int tid = threadIdx.x, w = tid >> 6, lane = tid & 63;

    const float* cb = c + b * 25;
    float fx = cb[16], sk = cb[17], cx = cb[18];
    float fy = cb[20], cy = cb[21];
    float ox = cb[3], oy = cb[7], oz = cb[11];

    // ---- ray setup: 4 rays per thread ----
    float px[RPT], py[RPT], pz[RPT], pn[RPT], dep[RPT], mxs[RPT];
    #pragma unroll
    for (int r = 0; r < RPT; ++r) {
        int m = tile * RAYS_PB + lane + 64 * r;
        int mm = min(m, M - 1);
        int i = mm / res, j = mm - i * res;
        float x = (j + 0.5f) / (float)res;
        float y = (i + 0.5f) / (float)res;
        float xl = (x - cx + cy * sk / fy - sk * y / fy) / fx;
        float yl = (y - cy) / fy;
        float wx = cb[0] * xl + cb[1] * yl + cb[2] + cb[3];
        float wy = cb[4] * xl + cb[5] * yl + cb[6] + cb[7];
        float wz = cb[8] * xl + cb[9] * yl + cb[10] + cb[11];
        float dx = wx - ox, dy = wy - oy, dz = wz - oz;
        float nrm = fmaxf(sqrtf(dx * dx + dy * dy + dz * dz), 1e-12f);
        dx /= nrm; dy /= nrm; dz /= nrm;
        float d = depth[(size_t)b * M + mm];
        dep[r] = d;
        px[r] = fmaf(d, dx, ox);
        py[r] = fmaf(d, dy, oy);
        pz[r] = fmaf(d, dz, oz);
        pn[r] = px[r] * px[r] + py[r] * py[r] + pz[r] * pz[r];
        mxs[r] = -3.4e38f;
    }

    // ---- point sweep: lane-resident points + readlane broadcast ----
    const float* pcb = pc + (size_t)b * N * 3;
    float mdl = 0.0f;   // squared distances >= 0
    const int SWEEP = WAVES * 64 * PPL;   // 2048 points per block sweep
    for (int n0 = 0; n0 < N; n0 += SWEEP) {
        int idx0 = n0 + (w * 64 + lane) * PPL;
        float4 qa, qb, qc, qd;
        if (idx0 + PPL <= N) {
            // 4 consecutive points = 48 B = 3 aligned float4 loads
            const float4* s4 = (const float4*)(pcb + (size_t)idx0 * 3);
            float4 f0 = s4[0], f1 = s4[1], f2 = s4[2];
            qa = make_float4(f0.x, f0.y, f0.z, 0.f);
            qb = make_float4(f0.w, f1.x, f1.y, 0.f);
            qc = make_float4(f1.z, f1.w, f2.x, 0.f);
            qd = make_float4(f2.y, f2.z, f2.w, 0.f);
        } else {
            // tail: clamped duplicates (harmless for max-reductions)
            int i0 = min(idx0,     N - 1) * 3;
            int i1 = min(idx0 + 1, N - 1) * 3;
            int i2 = min(idx0 + 2, N - 1) * 3;
            int i3 = min(idx0 + 3, N - 1) * 3;
            qa = make_float4(pcb[i0], pcb[i0 + 1], pcb[i0 + 2], 0.f);
            qb = make_float4(pcb[i1], pcb[i1 + 1], pcb[i1 + 2], 0.f);
            qc = make_float4(pcb[i2], pcb[i2 + 1], pcb[i2 + 2], 0.f);
            qd = make_float4(pcb[i3], pcb[i3 + 1], pcb[i3 + 2], 0.f);
        }
        // qw = -0.5|q|^2 ; maxdist partials (exact f32)
        qa.w = -0.5f * (qa.x * qa.x + qa.y * qa.y + qa.z * qa.z);
        qb.w = -0.5f * (qb.x * qb.x + qb.y * qb.y + qb.z * qb.z);
        qc.w = -0.5f * (qc.x * qc.x + qc.y * qc.y + qc.z * qc.z);
        qd.w = -0.5f * (qd.x * qd.x + qd.y * qd.y + qd.z * qd.z);
        {
            float ax = qa.x - ox, ay = qa.y - oy, az = qa.z - oz;
            float bx = qb.x - ox, by = qb.y - oy, bz = qb.z - oz;
            float cx2 = qc.x - ox, cy2 = qc.y - oy, cz2 = qc.z - oz;
            float dx2 = qd.x - ox, dy2 = qd.y - oy, dz2 = qd.z - oz;
            mdl = fmaxf(mdl, fmaxf(
                fmaxf(ax*ax + ay*ay + az*az, bx*bx + by*by + bz*bz),
                fmaxf(cx2*cx2 + cy2*cy2 + cz2*cz2, dx2*dx2 + dy2*dy2 + dz2*dz2)));
        }

        // ---- broadcast sweep over the wave's 256 points ----
        for (int g = 0; g < 64; ++g) {
            {
                float axv = rl(qa.x, g), ayv = rl(qa.y, g);
                float azv = rl(qa.z, g), awv = rl(qa.w, g);
                float bxv = rl(qb.x, g), byv = rl(qb.y, g);
                float bzv = rl(qb.z, g), bwv = rl(qb.w, g);
                #pragma unroll
                for (int r = 0; r < RPT; ++r) {
                    float sa = fmaf(px[r], axv, fmaf(py[r], ayv, fmaf(pz[r], azv, awv)));
                    float sb = fmaf(px[r], bxv, fmaf(py[r], byv, fmaf(pz[r], bzv, bwv)));
                    mxs[r] = fmaxf(mxs[r], fmaxf(sa, sb));   // -> v_max3_f32
                }
            }
            {
                float axv = rl(qc.x, g), ayv = rl(qc.y, g);
                float azv = rl(qc.z, g), awv = rl(qc.w, g);
                float bxv = rl(qd.x, g), byv = rl(qd.y, g);
                float bzv = rl(qd.z, g), bwv = rl(qd.w, g);
                #pragma unroll
                for (int r = 0; r < RPT; ++r) {
                    float sa = fmaf(px[r], axv, fmaf(py[r], ayv, fmaf(pz[r], azv, awv)));
                    float sb = fmaf(px[r], bxv, fmaf(py[r], byv, fmaf(pz[r], bzv, bwv)));
                    mxs[r] = fmaxf(mxs[r], fmaxf(sa, sb));
                }
            }
        }
    }

    // ---- per-wave maxdist partial + per-ray max handoff ----
    for (int off = 32; off; off >>= 1) mdl = fmaxf(mdl, __shfl_down(mdl, off));
    if (lane == 0) smax[w] = mdl;
    #pragma unroll
    for (int r = 0; r < RPT; ++r) red[w][lane + 64 * r] = mxs[r];
    __syncthreads();

    // ---- combine: thread tid (<256) owns ray tid ----
    float s = 0.f, cnt = 0.f;
    if (tid < RAYS_PB) {
        float m2 = smax[0];
        #pragma unroll
        for (int ww = 1; ww < WAVES; ++ww) m2 = fmaxf(m2, smax[ww]);
        float thr = sqrtf(m2);

        float mx = red[0][tid];
        #pragma unroll
        for (int ww = 1; ww < WAVES; ++ww) mx = fmaxf(mx, red[ww][tid]);
        // ray tid's pn/dep live in this thread's slot r == w (static select)
        float pnk = pn[0], dk = dep[0];
        #pragma unroll
        for (int r = 1; r < RPT; ++r) if (w == r) { pnk = pn[r]; dk = dep[r]; }
        int m = tile * RAYS_PB + tid;
        if (m < M) {
            float md = fmaxf(fmaf(-2.0f, mx, pnk), 0.0f);
            if (dk < thr) { s = md; cnt = 1.0f; }
        }
    }
    for (int off = 32; off; off >>= 1) {
        s += __shfl_down(s, off);
        cnt += __shfl_down(cnt, off);
    }
    if (tid < RAYS_PB && lane == 0) { bs[w] = s; bc[w] = cnt; }
    __syncthreads();
    if (tid == 0) {
        float S = 0.f, C = 0.f;
        #pragma unroll
        for (int ww = 0; ww < RAYS_PB / 64; ++ww) { S += bs[ww]; C += bc[ww]; }
        partial[(size_t)b * gridDim.x + blockIdx.x] = make_float2(S, C);
    }
}

// ---------------------------------------------------------------------------
// Finalize: ONE block; wave w reduces batch w's ntiles partials.
// ---------------------------------------------------------------------------
__global__ __launch_bounds__(1024) void finalize_kernel(
    const float2* __restrict__ partial, float* __restrict__ out,
    int ntiles, int B)
{
    int w = threadIdx.x >> 6, lane = threadIdx.x & 63;
    if (w >= B) return;
    float S = 0.f, C = 0.f;
    for (int i = lane; i < ntiles; i += 64) {
        float2 p = partial[(size_t)w * ntiles + i];
        S += p.x; C += p.y;
    }
    for (int off = 32; off; off >>= 1) {
        S += __shfl_down(S, off);
        C += __shfl_down(C, off);
    }
    if (lane == 0) out[w] = S / fmaxf(C, 1.0f);
}

extern "C" void kernel_launch(void* const* d_in, const int* in_sizes, int n_in,
                              void* d_out, int out_size, void* d_ws, size_t ws_size,
                              hipStream_t stream) {
    const float* c     = (const float*)d_in[0];
    const float* depth = (const float*)d_in[1];
    const float* pc    = (const float*)d_in[2];

    int B = in_sizes[0] / 25;
    int M = in_sizes[1] / B;
    int N = in_sizes[2] / (3 * B);
    int res = 1;
    while (res * res < M) ++res;

    float2* partial = (float2*)d_ws;

    int ntiles = (M + RAYS_PB - 1) / RAYS_PB;

    chamfer_main<<<dim3(ntiles, B), TPB, 0, stream>>>(c, depth, pc, partial,
                                                      res, M, N);
    finalize_kernel<<<1, B * 64, 0, stream>>>(partial, (float*)d_out,
                                              ntiles, B);
}

// Round 11
// 23.111 us; speedup vs baseline: 1.4505x; 1.4020x over previous
//
#include <hip/hip_runtime.h>
#include <math.h>

#define TPB 512
#define WAVES 8
#define RAYS_PB 256      // 8 waves x 32 rays
#define MAXPTS 2048      // points staged per LDS chunk
#define PTILE 32

typedef short short8 __attribute__((ext_vector_type(8)));
typedef float f32x16 __attribute__((ext_vector_type(16)));

__device__ __forceinline__ unsigned int f2bf(float f) {
    unsigned int u = __float_as_uint(f);
    u += 0x7FFFu + ((u >> 16) & 1u);   // round-to-nearest-even
    return u >> 16;
}

// ---------------------------------------------------------------------------
// Fused MFMA chamfer: grid = (ceil(M/256), B), block = 512 (8 waves).
// Wave w owns rays [w*32, w*32+32) of the block's 256; sweeps ALL N points.
//   S[r,c] = p4[r] . q4[c],  p4=(p,1) q4=(q,-0.5|q|^2)  -> bf16 MFMA 32x32x16
//   (A elems 4..7 = 0  =>  B lanes/elems beyond k=3 are don't-care)
//   min_n d2 = pn - 2*max_n S   (pn, maxdist, mask all exact f32)
// Per point-tile: ONE ds_read_b64 + ONE MFMA + 16 v_max. Deterministic.
// ---------------------------------------------------------------------------
__global__ __launch_bounds__(TPB) void chamfer_main(
    const float* __restrict__ c, const float* __restrict__ depth,
    const float* __restrict__ pc, float2* __restrict__ partial,
    int res, int M, int N)
{
    __shared__ uint2 spts[MAXPTS];            // bf16x4 packed points, 16 KB
    __shared__ float redR[WAVES][32][33];     // 33.8 KB (padded cols)
    __shared__ float pnL[RAYS_PB], depL[RAYS_PB];
    __shared__ float smax[WAVES];
    __shared__ float bs[4], bc[4];

    int tile = blockIdx.x, b = blockIdx.y;
    int tid = threadIdx.x, w = tid >> 6, lane = tid & 63;
    int colb = lane & 31, hh = lane >> 5;

    const float* cb = c + b * 25;
    float fx = cb[16], sk = cb[17], cx = cb[18];
    float fy = cb[20], cy = cb[21];
    float ox = cb[3], oy = cb[7], oz = cb[11];

    // ---- ray setup: wave w, row colb -> ray tile*256 + w*32 + colb ----
    short8 afrag = {0, 0, 0, 0, 0, 0, 0, 0};
    {
        int m = tile * RAYS_PB + w * 32 + colb;
        int mm = min(m, M - 1);
        int i = mm / res, j = mm - i * res;
        float x = (j + 0.5f) / (float)res;
        float y = (i + 0.5f) / (float)res;
        float xl = (x - cx + cy * sk / fy - sk * y / fy) / fx;
        float yl = (y - cy) / fy;
        float wx = cb[0] * xl + cb[1] * yl + cb[2] + cb[3];
        float wy = cb[4] * xl + cb[5] * yl + cb[6] + cb[7];
        float wz = cb[8] * xl + cb[9] * yl + cb[10] + cb[11];
        float dx = wx - ox, dy = wy - oy, dz = wz - oz;
        float nrm = fmaxf(sqrtf(dx * dx + dy * dy + dz * dz), 1e-12f);
        dx /= nrm; dy /= nrm; dz /= nrm;
        float d = depth[(size_t)b * M + mm];
        float px_ = fmaf(d, dx, ox);
        float py_ = fmaf(d, dy, oy);
        float pz_ = fmaf(d, dz, oz);
        float pn_ = px_ * px_ + py_ * py_ + pz_ * pz_;
        if (hh == 0) {
            pnL[w * 32 + colb] = pn_;
            depL[w * 32 + colb] = d;
            afrag[0] = (short)f2bf(px_);
            afrag[1] = (short)f2bf(py_);
            afrag[2] = (short)f2bf(pz_);
            afrag[3] = (short)0x3F80;   // 1.0 bf16
        }
    }

    const f32x16 zacc = {0.f,0.f,0.f,0.f,0.f,0.f,0.f,0.f,
                         0.f,0.f,0.f,0.f,0.f,0.f,0.f,0.f};
    float mx[16];
    #pragma unroll
    for (int r = 0; r < 16; ++r) mx[r] = -3.4e38f;

    // ---- stage + MFMA-sweep all N points (chunked) ----
    float mdl = 0.0f;
    for (int n0 = 0; n0 < N; n0 += MAXPTS) {
        int kc = min(N - n0, MAXPTS);
        int kcp = ((kc + PTILE - 1) / PTILE) * PTILE;
        if (n0) __syncthreads();
        const float* src = pc + ((size_t)b * N + n0) * 3;

        int g4 = kc >> 2;
        const float4* s4 = (const float4*)src;
        for (int g = tid; g < g4; g += TPB) {
            float4 f0 = s4[3 * g], f1 = s4[3 * g + 1], f2 = s4[3 * g + 2];
            float qx0 = f0.x, qy0 = f0.y, qz0 = f0.z;
            float qx1 = f0.w, qy1 = f1.x, qz1 = f1.y;
            float qx2 = f1.z, qy2 = f1.w, qz2 = f2.x;
            float qx3 = f2.y, qy3 = f2.z, qz3 = f2.w;
            float w0 = -0.5f * (qx0*qx0 + qy0*qy0 + qz0*qz0);
            float w1 = -0.5f * (qx1*qx1 + qy1*qy1 + qz1*qz1);
            float w2 = -0.5f * (qx2*qx2 + qy2*qy2 + qz2*qz2);
            float w3 = -0.5f * (qx3*qx3 + qy3*qy3 + qz3*qz3);
            spts[4*g+0] = make_uint2(f2bf(qx0) | (f2bf(qy0) << 16), f2bf(qz0) | (f2bf(w0) << 16));
            spts[4*g+1] = make_uint2(f2bf(qx1) | (f2bf(qy1) << 16), f2bf(qz1) | (f2bf(w1) << 16));
            spts[4*g+2] = make_uint2(f2bf(qx2) | (f2bf(qy2) << 16), f2bf(qz2) | (f2bf(w2) << 16));
            spts[4*g+3] = make_uint2(f2bf(qx3) | (f2bf(qy3) << 16), f2bf(qz3) | (f2bf(w3) << 16));
            float a0 = qx0 - ox, a1 = qy0 - oy, a2 = qz0 - oz;
            float b0 = qx1 - ox, b1 = qy1 - oy, b2 = qz1 - oz;
            float c0 = qx2 - ox, c1 = qy2 - oy, c2 = qz2 - oz;
            float d0 = qx3 - ox, d1 = qy3 - oy, d2 = qz3 - oz;
            mdl = fmaxf(mdl, fmaxf(
                fmaxf(a0*a0 + a1*a1 + a2*a2, b0*b0 + b1*b1 + b2*b2),
                fmaxf(c0*c0 + c1*c1 + c2*c2, d0*d0 + d1*d1 + d2*d2)));
        }
        for (int p = (g4 << 2) + tid; p < kc; p += TPB) {
            float qx = src[3*p], qy = src[3*p+1], qz = src[3*p+2];
            float qn = qx*qx + qy*qy + qz*qz;
            spts[p] = make_uint2(f2bf(qx) | (f2bf(qy) << 16),
                                 f2bf(qz) | (f2bf(-0.5f * qn) << 16));
            float dx = qx - ox, dy = qy - oy, dz = qz - oz;
            mdl = fmaxf(mdl, dx*dx + dy*dy + dz*dz);
        }
        for (int p = kc + tid; p < kcp; p += TPB)
            spts[p] = make_uint2(0u, 0xC61C0000u);   // qw = -10000 -> never max
        __syncthreads();

        int ntt = kcp >> 5;
        #pragma unroll 2
        for (int t = 0; t < ntt; ++t) {
            uint2 qv = spts[t * 32 + colb];          // b64; lanes 32-63 dup (free)
            union { uint4 u; short8 s; } bu;
            bu.u = make_uint4(qv.x, qv.y, 0u, 0u);
            f32x16 dacc = __builtin_amdgcn_mfma_f32_32x32x16_bf16(
                afrag, bu.s, zacc, 0, 0, 0);
            #pragma unroll
            for (int r = 0; r < 16; ++r) mx[r] = fmaxf(mx[r], dacc[r]);
        }
    }

    // ---- per-wave maxdist + dump per-(row,col) maxes to LDS ----
    for (int off = 32; off; off >>= 1) mdl = fmaxf(mdl, __shfl_down(mdl, off));
    if (lane == 0) smax[w] = mdl;
    #pragma unroll
    for (int r = 0; r < 16; ++r) {
        int row = (r & 3) + 8 * (r >> 2) + 4 * hh;   // verified C/D layout
        redR[w][row][colb] = mx[r];
    }
    __syncthreads();

    // ---- epilogue: thread tid (<256) owns ray tid; reduce over 32 cols ----
    float s = 0.f, cnt = 0.f;
    if (tid < RAYS_PB) {
        float m2 = smax[0];
        #pragma unroll
        for (int ww = 1; ww < WAVES; ++ww) m2 = fmaxf(m2, smax[ww]);
        float thr = sqrtf(m2);

        int w2 = tid >> 5, row = tid & 31;
        float mxx = redR[w2][row][0];
        #pragma unroll
        for (int col = 1; col < 32; ++col) mxx = fmaxf(mxx, redR[w2][row][col]);

        int mray = tile * RAYS_PB + tid;
        if (mray < M) {
            float md = fmaxf(fmaf(-2.0f, mxx, pnL[tid]), 0.0f);
            if (depL[tid] < thr) { s = md; cnt = 1.0f; }
        }
    }
    for (int off = 32; off; off >>= 1) {
        s += __shfl_down(s, off);
        cnt += __shfl_down(cnt, off);
    }
    if (tid < RAYS_PB && lane == 0) { bs[w] = s; bc[w] = cnt; }
    __syncthreads();
    if (tid == 0) {
        float S = 0.f, C = 0.f;
        #pragma unroll
        for (int ww = 0; ww < 4; ++ww) { S += bs[ww]; C += bc[ww]; }
        partial[(size_t)b * gridDim.x + blockIdx.x] = make_float2(S, C);
    }
}

// ---------------------------------------------------------------------------
// Finalize: ONE block; wave w reduces batch w's ntiles partials.
// ---------------------------------------------------------------------------
__global__ __launch_bounds__(1024) void finalize_kernel(
    const float2* __restrict__ partial, float* __restrict__ out,
    int ntiles, int B)
{
    int w = threadIdx.x >> 6, lane = threadIdx.x & 63;
    if (w >= B) return;
    float S = 0.f, C = 0.f;
    for (int i = lane; i < ntiles; i += 64) {
        float2 p = partial[(size_t)w * ntiles + i];
        S += p.x; C += p.y;
    }
    for (int off = 32; off; off >>= 1) {
        S += __shfl_down(S, off);
        C += __shfl_down(C, off);
    }
    if (lane == 0) out[w] = S / fmaxf(C, 1.0f);
}

extern "C" void kernel_launch(void* const* d_in, const int* in_sizes, int n_in,
                              void* d_out, int out_size, void* d_ws, size_t ws_size,
                              hipStream_t stream) {
    const float* c     = (const float*)d_in[0];
    const float* depth = (const float*)d_in[1];
    const float* pc    = (const float*)d_in[2];

    int B = in_sizes[0] / 25;
    int M = in_sizes[1] / B;
    int N = in_sizes[2] / (3 * B);
    int res = 1;
    while (res * res < M) ++res;

    float2* partial = (float2*)d_ws;
    int ntiles = (M + RAYS_PB - 1) / RAYS_PB;

    chamfer_main<<<dim3(ntiles, B), TPB, 0, stream>>>(c, depth, pc, partial,
                                                      res, M, N);
    finalize_kernel<<<1, B * 64, 0, stream>>>(partial, (float*)d_out,
                                              ntiles, B);
}